// Round 6
// baseline (614.493 us; speedup 1.0000x reference)
//
#include <hip/hip_runtime.h>
#include <stdint.h>

// ============================================================
// Adaptive log-softmax NLL, MI355X gfx950.  Round 11.
// R10: logit_all stuck at 158us across 3 variants (latency-bound);
// ~237us hidden below top-5 cutoff -> k_mid's 305MB W-convert sweep
// is the prime suspect.  This round DELETES the W pre-conversion:
// logit reads fp32 W directly with in-register v_perm pack.
//  - W k-step addressing = imm offsets only (<=3968B fits 13-bit imm)
//  - pointer clamp at setup + padded bias -> no in-loop masks
//  - depth-2 pipeline: issue fp32 loads k+1 -> MFMA(k) -> pack(k+1)
// Kernels: pre {hidden conv, transposes, bias pads} -> gemm_all ->
// logit_all (fp32 W) -> finalize.
// ============================================================

typedef __attribute__((ext_vector_type(8))) short short8;   // 8 bf16
typedef __attribute__((ext_vector_type(4))) float f32x4;

__device__ __forceinline__ float bf2f(unsigned short u) {
    union { unsigned int i; float f; } v; v.i = ((unsigned int)u) << 16; return v.f;
}
__device__ __forceinline__ unsigned short f2bf(float f) {
    union { float f; unsigned int i; } v; v.f = f;
    unsigned int u = v.i;
    return (unsigned short)((u + 0x7fffu + ((u >> 16) & 1u)) >> 16);  // RNE
}
__device__ __forceinline__ float wave_sum(float v) {
    v += __shfl_xor(v, 1, 64);  v += __shfl_xor(v, 2, 64);
    v += __shfl_xor(v, 4, 64);  v += __shfl_xor(v, 8, 64);
    v += __shfl_xor(v, 16, 64); v += __shfl_xor(v, 32, 64);
    return v;
}
// pack 8 fp32 -> 8 bf16 (truncation) via v_perm
__device__ __forceinline__ short8 pack8(float4 a, float4 b) {
    union { int4 i; short8 s; } r;
    r.i.x = __builtin_amdgcn_perm(__float_as_uint(a.y), __float_as_uint(a.x), 0x07060302u);
    r.i.y = __builtin_amdgcn_perm(__float_as_uint(a.w), __float_as_uint(a.z), 0x07060302u);
    r.i.z = __builtin_amdgcn_perm(__float_as_uint(b.y), __float_as_uint(b.x), 0x07060302u);
    r.i.w = __builtin_amdgcn_perm(__float_as_uint(b.w), __float_as_uint(b.z), 0x07060302u);
    return r.s;
}

// ================= pre =================
__device__ __forceinline__ void dev_transpose(int bx, int by,
                                              const float* __restrict__ src,
                                              unsigned short* __restrict__ dst,
                                              int K, int N) {
    __shared__ unsigned short tile[32][33];
    int k0 = by * 32, n0 = bx * 32;
    int tx = threadIdx.x & 31, ty = threadIdx.x >> 5;
#pragma unroll
    for (int j = 0; j < 4; ++j) {
        int k = k0 + ty + j * 8, n = n0 + tx;
        float v = (n < N) ? src[(size_t)k * N + n] : 0.f;
        tile[ty + j * 8][tx] = f2bf(v);
    }
    __syncthreads();
#pragma unroll
    for (int j = 0; j < 4; ++j) {
        int n = n0 + ty + j * 8, k = k0 + tx;
        if (n < N) dst[(size_t)n * K + k] = tile[tx][ty + j * 8];
    }
}

__device__ __forceinline__ void dev_biasfill(int bid, const float* __restrict__ b,
                                             float* __restrict__ bp, int vocab, int padded) {
    int i = bid * 256 + threadIdx.x;
    if (i < padded) bp[i] = (i < vocab) ? b[i] : -1e30f;
}

// pre ranges: [0,1024) hidden | [1024,2048) T0 | [2048,2304) T1 |
// [2304,2368) T2 | [2368,2400) T3 | [2400,2479) b0p | [2479,2558) b1p |
// [2558,3188) b2p | [3188,3460) b3p
__global__ __launch_bounds__(256)
void k_pre(const float* __restrict__ hidden, unsigned short* __restrict__ hid_bf,
           const float* __restrict__ proj0, unsigned short* __restrict__ pT0,
           const float* __restrict__ proj1, unsigned short* __restrict__ pT1,
           const float* __restrict__ proj2, unsigned short* __restrict__ pT2,
           const float* __restrict__ proj3, unsigned short* __restrict__ pT3,
           const float* __restrict__ b0, float* __restrict__ b0p,
           const float* __restrict__ b1, float* __restrict__ b1p,
           const float* __restrict__ b2, float* __restrict__ b2p,
           const float* __restrict__ b3, float* __restrict__ b3p) {
    int bid = blockIdx.x, tid = threadIdx.x;
    if (bid < 1024) {
        int i = bid * 256 + tid;   // 262144 float4 exactly
        float4 v = ((const float4*)hidden)[i];
        ushort4 o;
        o.x = f2bf(v.x); o.y = f2bf(v.y); o.z = f2bf(v.z); o.w = f2bf(v.w);
        ((ushort4*)hid_bf)[i] = o;
    }
    else if (bid < 2048) { int i = bid - 1024; dev_transpose(i & 31, i >> 5, proj0, pT0, 1024, 1024); }
    else if (bid < 2304) { int i = bid - 2048; dev_transpose(i & 7,  i >> 3, proj1, pT1, 1024, 256); }
    else if (bid < 2368) { int i = bid - 2304; dev_transpose(i & 1,  i >> 1, proj2, pT2, 1024, 64); }
    else if (bid < 2400) { int i = bid - 2368; dev_transpose(0,      i,      proj3, pT3, 1024, 16); }
    else if (bid < 2479) dev_biasfill(bid - 2400, b0, b0p, 20000, 20096);
    else if (bid < 2558) dev_biasfill(bid - 2479, b1, b1p, 20000, 20096);
    else if (bid < 3188) dev_biasfill(bid - 2558, b2, b2p, 160000, 161280);
    else                 dev_biasfill(bid - 3188, b3, b3p, 67735, 69632);
}

// ================= projection GEMM (frag-major out) =================
#define BM 128
#define BN 128
#define BK 64
#define LDT 72
template <int NK32O>
__device__ __forceinline__ void dev_gemm(unsigned short* __restrict__ ls,
                                         int bx, int by,
                                         const unsigned short* __restrict__ A, int lda,
                                         const unsigned short* __restrict__ B, int ldb,
                                         unsigned short* __restrict__ Cf,
                                         int N, int K) {
    unsigned short* lsA = ls;
    unsigned short* lsB = ls + BM * LDT;
    int tid = threadIdx.x;
    int mBase = bx * BM, nBase = by * BN;
    int wid = tid >> 6, lane = tid & 63;
    int wr = wid >> 1, wc = wid & 1;
    int q = lane >> 4, ln = lane & 15;
    f32x4 acc[4][4] = {};

    for (int k0 = 0; k0 < K; k0 += BK) {
        __syncthreads();
        int ch = tid & 7;
#pragma unroll
        for (int p = 0; p < 4; ++p) {
            int r = p * 32 + (tid >> 3);
            *(uint4*)(&lsA[r * LDT + ch * 8]) =
                *(const uint4*)(A + (size_t)(mBase + r) * lda + k0 + ch * 8);
        }
#pragma unroll
        for (int p = 0; p < 4; ++p) {
            int r = p * 32 + (tid >> 3);
            uint4 v = {0u, 0u, 0u, 0u};
            if (nBase + r < N)
                v = *(const uint4*)(B + (size_t)(nBase + r) * ldb + k0 + ch * 8);
            *(uint4*)(&lsB[r * LDT + ch * 8]) = v;
        }
        __syncthreads();
#pragma unroll
        for (int ks = 0; ks < 2; ++ks) {
            short8 af[4], bfr[4];
#pragma unroll
            for (int mi = 0; mi < 4; ++mi)
                af[mi] = *(const short8*)(&lsA[(wr * 64 + mi * 16 + ln) * LDT + ks * 32 + q * 8]);
#pragma unroll
            for (int ni = 0; ni < 4; ++ni)
                bfr[ni] = *(const short8*)(&lsB[(wc * 64 + ni * 16 + ln) * LDT + ks * 32 + q * 8]);
#pragma unroll
            for (int mi = 0; mi < 4; ++mi)
#pragma unroll
                for (int ni = 0; ni < 4; ++ni)
                    acc[mi][ni] = __builtin_amdgcn_mfma_f32_16x16x32_bf16(
                        af[mi], bfr[ni], acc[mi][ni], 0, 0, 0);
        }
    }
#pragma unroll
    for (int ni = 0; ni < 4; ++ni) {
        int col = nBase + wc * 64 + ni * 16 + ln;
        if (col < N) {
            int k32 = col >> 5, qc = (col >> 3) & 3, j = col & 7;
#pragma unroll
            for (int mi = 0; mi < 4; ++mi) {
                int m16 = (mBase >> 4) + wr * 4 + mi;
                size_t base = ((size_t)m16 * NK32O + k32) * 512 + (size_t)qc * 128 + j;
#pragma unroll
                for (int r = 0; r < 4; ++r) {
                    int mrem = q * 4 + r;
                    Cf[base + mrem * 8] = f2bf(acc[mi][ni][r]);
                }
            }
        }
    }
}

// gemm ranges: [0,64) c0 | [64,80) c1 | [80,88) c2 | [88,96) c3
__global__ __launch_bounds__(256)
void k_gemm_all(const unsigned short* __restrict__ hid_bf,
                const unsigned short* __restrict__ pT0, const unsigned short* __restrict__ pT1,
                const unsigned short* __restrict__ pT2, const unsigned short* __restrict__ pT3,
                unsigned short* __restrict__ h0f, unsigned short* __restrict__ h1f,
                unsigned short* __restrict__ h2f, unsigned short* __restrict__ h3f) {
    __shared__ unsigned short ls[(BM + BN) * LDT];
    int bid = blockIdx.x;
    if (bid < 64)      dev_gemm<32>(ls, bid & 7, bid >> 3, hid_bf, 1024, pT0, 1024, h0f, 1024, 1024);
    else if (bid < 80) { int i = bid - 64; dev_gemm<8>(ls, i & 7, i >> 3, hid_bf, 1024, pT1, 1024, h1f, 256, 1024); }
    else if (bid < 88) dev_gemm<2>(ls, bid - 80, 0, hid_bf, 1024, pT2, 1024, h2f, 64, 1024);
    else               dev_gemm<1>(ls, bid - 88, 0, hid_bf, 1024, pT3, 1024, h3f, 16, 1024);
}

// ================= logit: fp32-W dual-stream (c0, c1) =================
// Depth-2 pipeline: issue fp32 loads k+1 -> MFMA(k) -> pack(k+1).
// W k-offsets are imm-only (ks*128B <= 3968).  Pointer clamped at setup;
// pad cols get bias -1e30 -> exp()=0.
template <int NK32, int KD>
__device__ __forceinline__ void dev_stream(int f,
                const unsigned short* __restrict__ Af,
                const float* __restrict__ W,        // fp32 [vocab][KD]
                const float* __restrict__ biasp,
                float* __restrict__ rowsum, int vocabm1) {
    int u = f & 63;
    int xb = u >> 3;
    int yb = ((f >> 6) << 3) + (u & 7);   // same (u&7) => same XCD
    if (yb >= 157) return;

    int tid = threadIdx.x, wid = tid >> 6, lane = tid & 63;
    int wr = wid >> 1, wc = wid & 1;
    int q = lane >> 4, ln = lane & 15;
    int mb = xb * 128 + wr * 64;
    int nb = yb * 128 + wc * 64;

    const unsigned short* Ab = Af + (size_t)(mb >> 4) * NK32 * 512 + lane * 8;
    const float* Wp[4];
#pragma unroll
    for (int ni = 0; ni < 4; ++ni) {
        int rw = min(nb + ni * 16 + ln, vocabm1);
        Wp[ni] = W + (size_t)rw * KD + q * 8;
    }

    f32x4 acc[4][4] = {};
    short8 a0[4], a1[4], w0[4], w1[4];
    float4 fa[4], fb[4];
    auto LA = [&](short8* d, int kk) {
#pragma unroll
        for (int mi = 0; mi < 4; ++mi)
            d[mi] = *(const short8*)(Ab + ((size_t)mi * NK32 + kk) * 512);
    };
    auto LWF = [&](int kk) {
#pragma unroll
        for (int ni = 0; ni < 4; ++ni) {
            fa[ni] = *(const float4*)(Wp[ni] + kk * 32);
            fb[ni] = *(const float4*)(Wp[ni] + kk * 32 + 4);
        }
    };
    auto PK = [&](short8* d) {
#pragma unroll
        for (int ni = 0; ni < 4; ++ni) d[ni] = pack8(fa[ni], fb[ni]);
    };
    auto FM = [&](short8* a, short8* w) {
#pragma unroll
        for (int mi = 0; mi < 4; ++mi)
#pragma unroll
            for (int ni = 0; ni < 4; ++ni)
                acc[mi][ni] = __builtin_amdgcn_mfma_f32_16x16x32_bf16(
                    a[mi], w[ni], acc[mi][ni], 0, 0, 0);
    };

    LA(a0, 0); LWF(0); PK(w0);
#pragma unroll
    for (int ks = 0; ks < NK32; ks += 2) {
        LA(a1, ks + 1); LWF(ks + 1);          // issue k+1 (NK32 even)
        FM(a0, w0);                            // compute k (cover for loads)
        PK(w1);                                // pack k+1
        if (ks + 2 < NK32) { LA(a0, ks + 2); LWF(ks + 2); }
        FM(a1, w1);
        if (ks + 2 < NK32) PK(w0);
    }

    float s[4][4];
#pragma unroll
    for (int mi = 0; mi < 4; ++mi)
#pragma unroll
        for (int r = 0; r < 4; ++r) s[mi][r] = 0.f;
#pragma unroll
    for (int ni = 0; ni < 4; ++ni) {
        float b = biasp[nb + ni * 16 + ln];
#pragma unroll
        for (int mi = 0; mi < 4; ++mi)
#pragma unroll
            for (int r = 0; r < 4; ++r)
                s[mi][r] += __expf(acc[mi][ni][r] + b);
    }
#pragma unroll
    for (int mi = 0; mi < 4; ++mi)
#pragma unroll
        for (int r = 0; r < 4; ++r) {
            float v = s[mi][r];
            v += __shfl_xor(v, 1, 64);
            v += __shfl_xor(v, 2, 64);
            v += __shfl_xor(v, 4, 64);
            v += __shfl_xor(v, 8, 64);
            s[mi][r] = v;
        }
    int sl = yb & 31;
    if (ln == 0) {
#pragma unroll
        for (int mi = 0; mi < 4; ++mi)
#pragma unroll
            for (int r = 0; r < 4; ++r)
                atomicAdd(&rowsum[sl * 1024 + mb + mi * 16 + q * 4 + r], s[mi][r]);
    }
}

// ================= logit: fp32-W A-stationary tails (c2, c3) =================
// KDR = real row length (64 / 16).  c3 (KDR=16): q>=2 lanes use zero frags
// (h3f K-pad is also zero -> contributes 0).
template <int NK32, int KDR>
__device__ __forceinline__ void dev_tail(int bx, int by,
                const unsigned short* __restrict__ Af,
                const float* __restrict__ W,
                const float* __restrict__ biasp,
                float* __restrict__ rowsum, int ngroups, int vocabm1) {
    int tid = threadIdx.x;
    int wid = tid >> 6, lane = tid & 63;
    int q = lane >> 4, ln = lane & 15;
    int m16b = by * 16 + wid * 4;
    int u0 = bx * ngroups;

    short8 af[4][NK32];
#pragma unroll
    for (int mi = 0; mi < 4; ++mi)
#pragma unroll
        for (int ks = 0; ks < NK32; ++ks)
            af[mi][ks] = *(const short8*)(Af + ((size_t)(m16b + mi) * NK32 + ks) * 512 + lane * 8);

    float rs[4][4];
#pragma unroll
    for (int mi = 0; mi < 4; ++mi)
#pragma unroll
        for (int r = 0; r < 4; ++r) rs[mi][r] = 0.f;

    float4 fa[NK32], fb[NK32];
    auto LWF = [&](int u) {
        int rw = min(u * 16 + ln, vocabm1);
        const float* p = W + (size_t)rw * KDR + q * 8;
        if constexpr (KDR == 16) {
            if (q < 2) { fa[0] = *(const float4*)p; fb[0] = *(const float4*)(p + 4); }
            else       { fa[0] = float4{0,0,0,0};   fb[0] = float4{0,0,0,0}; }
        } else {
#pragma unroll
            for (int ks = 0; ks < NK32; ++ks) {
                fa[ks] = *(const float4*)(p + ks * 32);
                fb[ks] = *(const float4*)(p + ks * 32 + 4);
            }
        }
    };
    auto CG = [&](short8* w, int u) {
        f32x4 acc[4] = {};
#pragma unroll
        for (int ks = 0; ks < NK32; ++ks)
#pragma unroll
            for (int mi = 0; mi < 4; ++mi)
                acc[mi] = __builtin_amdgcn_mfma_f32_16x16x32_bf16(
                    af[mi][ks], w[ks], acc[mi], 0, 0, 0);
        float b = biasp[u * 16 + ln];
#pragma unroll
        for (int mi = 0; mi < 4; ++mi)
#pragma unroll
            for (int r = 0; r < 4; ++r)
                rs[mi][r] += __expf(acc[mi][r] + b);
    };

    short8 wA[NK32], wB[NK32];
    LWF(u0);
#pragma unroll
    for (int ks = 0; ks < NK32; ++ks) wA[ks] = pack8(fa[ks], fb[ks]);
    int g = 0;
    for (; g + 2 <= ngroups; g += 2) {
        LWF(u0 + g + 1);
        CG(wA, u0 + g);
#pragma unroll
        for (int ks = 0; ks < NK32; ++ks) wB[ks] = pack8(fa[ks], fb[ks]);
        if (g + 2 < ngroups) LWF(u0 + g + 2);
        CG(wB, u0 + g + 1);
        if (g + 2 < ngroups) {
#pragma unroll
            for (int ks = 0; ks < NK32; ++ks) wA[ks] = pack8(fa[ks], fb[ks]);
        }
    }
    if (g < ngroups) CG(wA, u0 + g);

    int sl = bx & 31;
#pragma unroll
    for (int mi = 0; mi < 4; ++mi)
#pragma unroll
        for (int r = 0; r < 4; ++r) {
            float v = rs[mi][r];
            v += __shfl_xor(v, 1, 64);
            v += __shfl_xor(v, 2, 64);
            v += __shfl_xor(v, 4, 64);
            v += __shfl_xor(v, 8, 64);
            if (ln == 0)
                atomicAdd(&rowsum[sl * 1024 + (m16b + mi) * 16 + q * 4 + r], v);
        }
}

// ================= gather =================
__device__ __forceinline__ float frag_dot(const unsigned short* __restrict__ hf,
                                          int NK32, int KdReal, int n,
                                          const float* __restrict__ wrow, int lane) {
    float s = 0.f;
    for (int c = lane; c * 8 < KdReal; c += 64) {
        int k32 = c >> 2, qq = c & 3;
        const unsigned short* p = hf + ((size_t)(n >> 4) * NK32 + k32) * 512 + (qq * 16 + (n & 15)) * 8;
#pragma unroll
        for (int j = 0; j < 8; ++j)
            s += bf2f(p[j]) * wrow[c * 8 + j];
    }
    return wave_sum(s);
}

__device__ __forceinline__ void dev_gather(int bid,
                         const unsigned short* __restrict__ h0f,
                         const unsigned short* __restrict__ h1f,
                         const unsigned short* __restrict__ h2f,
                         const unsigned short* __restrict__ h3f,
                         const float* __restrict__ W0, const float* __restrict__ b0,
                         const float* __restrict__ W1, const float* __restrict__ b1,
                         const float* __restrict__ W2, const float* __restrict__ b2,
                         const float* __restrict__ W3, const float* __restrict__ b3,
                         const float* __restrict__ cW, const float* __restrict__ cb,
                         const int* __restrict__ target,
                         float* __restrict__ rowsum0,
                         float* __restrict__ gat_head,
                         float* __restrict__ gat_tail) {
    int gw = bid * 4 + (threadIdx.x >> 6);
    int lane = threadIdx.x & 63;
    if (gw >= 1024) return;
    int n = gw;
    int t = target[n];

    float cl[3];
#pragma unroll
    for (int j = 0; j < 3; ++j)
        cl[j] = frag_dot(h0f, 32, 1024, n, cW + j * 1024, lane) + cb[j];
    if (lane == 0)
        atomicAdd(&rowsum0[n], __expf(cl[0]) + __expf(cl[1]) + __expf(cl[2]));

    float gh, gt = 0.f;
    if (t < 20000) {
        gh = frag_dot(h0f, 32, 1024, n, W0 + (size_t)t * 1024, lane) + b0[t];
    } else {
        int c, l, Kd, NK32;
        const unsigned short* h; const float* W; const float* b;
        if (t < 40000)       { c = 1; l = 20000;  Kd = 256; NK32 = 8; h = h1f; W = W1; b = b1; }
        else if (t < 200000) { c = 2; l = 40000;  Kd = 64;  NK32 = 2; h = h2f; W = W2; b = b2; }
        else                 { c = 3; l = 200000; Kd = 16;  NK32 = 1; h = h3f; W = W3; b = b3; }
        gh = cl[3 - c];
        gt = frag_dot(h, NK32, Kd, n, W + (size_t)(t - l) * Kd, lane) + b[t - l];
    }
    if (lane == 0) { gat_head[n] = gh; gat_tail[n] = gt; }
}

// ================= mega logit launch =================
// [0,1280) head | [1280,2560) c1 | [2560,3200) c2 | [3200,3712) c3 |
// [3712,3968) gather.
__global__ __launch_bounds__(256, 2)
void k_logit_all(const unsigned short* __restrict__ h0f, const unsigned short* __restrict__ h1f,
                 const unsigned short* __restrict__ h2f, const unsigned short* __restrict__ h3f,
                 const float* __restrict__ b0p, const float* __restrict__ b1p,
                 const float* __restrict__ b2p, const float* __restrict__ b3p,
                 const float* __restrict__ W0, const float* __restrict__ b0,
                 const float* __restrict__ W1, const float* __restrict__ b1,
                 const float* __restrict__ W2, const float* __restrict__ b2,
                 const float* __restrict__ W3, const float* __restrict__ b3,
                 const float* __restrict__ cW, const float* __restrict__ cb,
                 const int* __restrict__ target,
                 float* __restrict__ rowsum,
                 float* __restrict__ gat_head, float* __restrict__ gat_tail) {
    int bid = blockIdx.x;
    if (bid < 1280) {
        dev_stream<32, 1024>(bid, h0f, W0, b0p, rowsum, 19999);
    } else if (bid < 2560) {
        dev_stream<8, 256>(bid - 1280, h1f, W1, b1p, rowsum + 32768, 19999);
    } else if (bid < 3200) {
        int i = bid - 2560;
        dev_tail<2, 64>(i % 160, i / 160, h2f, W2, b2p, rowsum + 65536, 63, 159999);
    } else if (bid < 3712) {
        int i = bid - 3200;
        dev_tail<1, 16>(i & 127, i >> 7, h3f, W3, b3p, rowsum + 98304, 34, 67734);
    } else {
        dev_gather(bid - 3712, h0f, h1f, h2f, h3f, W0, b0, W1, b1, W2, b2, W3, b3,
                   cW, cb, target, rowsum, gat_head, gat_tail);
    }
}

// ================= finalize =================
__global__ void k_finalize(const float* __restrict__ rs,  // [4][32][1024]
                           const float* __restrict__ gat_head,
                           const float* __restrict__ gat_tail,
                           const int* __restrict__ target,
                           float* __restrict__ out) {
    __shared__ float red[16];
    int n = threadIdx.x;
    int t = target[n];
    float r0 = 0.f;
#pragma unroll
    for (int s = 0; s < 32; ++s) r0 += rs[s * 1024 + n];
    float nll = __logf(r0) - gat_head[n];
    int c = (t < 20000) ? 0 : (t < 40000) ? 1 : (t < 200000) ? 2 : 3;
    if (c > 0) {
        float rc = 0.f;
#pragma unroll
        for (int s = 0; s < 32; ++s) rc += rs[c * 32768 + s * 1024 + n];
        nll += __logf(rc) - gat_tail[n];
    }
    float sm = wave_sum(nll);
    int wid = n >> 6, lane = n & 63;
    if (lane == 0) red[wid] = sm;
    __syncthreads();
    if (n == 0) {
        float tot = 0.f;
#pragma unroll
        for (int i = 0; i < 16; ++i) tot += red[i];
        out[0] = tot / 1024.0f;
    }
}

// ============================================================
extern "C" void kernel_launch(void* const* d_in, const int* in_sizes, int n_in,
                              void* d_out, int out_size, void* d_ws, size_t ws_size,
                              hipStream_t stream) {
    const float* hidden = (const float*)d_in[0];
    const int*   target = (const int*)d_in[1];
    const float* W0 = (const float*)d_in[2];
    const float* b0 = (const float*)d_in[3];
    const float* proj0 = (const float*)d_in[4];
    const float* W1 = (const float*)d_in[5];
    const float* b1 = (const float*)d_in[6];
    const float* proj1 = (const float*)d_in[7];
    const float* W2 = (const float*)d_in[8];
    const float* b2 = (const float*)d_in[9];
    const float* proj2 = (const float*)d_in[10];
    const float* W3 = (const float*)d_in[11];
    const float* b3 = (const float*)d_in[12];
    const float* proj3 = (const float*)d_in[13];
    const float* cW = (const float*)d_in[14];
    const float* cb = (const float*)d_in[15];

    char* ws = (char*)d_ws;
    unsigned short* hid_bf = (unsigned short*)(ws + 0x000000);  // 2 MB
    unsigned short* pT0 = (unsigned short*)(ws + 0x200000);     // 2 MB
    unsigned short* pT1 = (unsigned short*)(ws + 0x400000);     // 512 KB
    unsigned short* pT2 = (unsigned short*)(ws + 0x480000);     // 128 KB
    unsigned short* pT3 = (unsigned short*)(ws + 0x4A0000);     // 32 KB
    unsigned short* h0f = (unsigned short*)(ws + 0x4A8000);     // 2 MB
    unsigned short* h1f = (unsigned short*)(ws + 0x6A8000);     // 512 KB
    unsigned short* h2f = (unsigned short*)(ws + 0x728000);     // 128 KB
    unsigned short* h3f = (unsigned short*)(ws + 0x748000);     // 64 KB (K padded 16->32, zeros)
    float* rowsum   = (float*)(ws + 0x758000);                  // [4][32][1024] = 512 KB
    float* gat_head = (float*)(ws + 0x7D8000);                  // 4 KB
    float* gat_tail = (float*)(ws + 0x7D9000);                  // 4 KB
    float* b0p = (float*)(ws + 0x05100000);                     // 20096 f
    float* b1p = (float*)(ws + 0x05114000);                     // 20096 f
    float* b2p = (float*)(ws + 0x05128000);                     // 161280 f
    float* b3p = (float*)(ws + 0x051C8000);                     // 69632 f

    hipMemsetAsync(ws + 0x748000, 0, 0x92000, stream);

    k_pre<<<3460, 256, 0, stream>>>(hidden, hid_bf,
                                    proj0, pT0, proj1, pT1, proj2, pT2, proj3, pT3,
                                    b0, b0p, b1, b1p, b2, b2p, b3, b3p);

    k_gemm_all<<<96, 256, 0, stream>>>(hid_bf, pT0, pT1, pT2, pT3, h0f, h1f, h2f, h3f);

    k_logit_all<<<3968, 256, 0, stream>>>(h0f, h1f, h2f, h3f,
                                          b0p, b1p, b2p, b3p,
                                          W0, b0, W1, b1, W2, b2, W3, b3,
                                          cW, cb, target, rowsum, gat_head, gat_tail);

    k_finalize<<<1, 1024, 0, stream>>>(rowsum, gat_head, gat_tail, target, (float*)d_out);
}